// Round 14
// baseline (232.251 us; speedup 1.0000x reference)
//
#include <hip/hip_runtime.h>

// Bidirectional GRU (H=32, input=1, B=2048, T=512) + MLP head, fully fused.
//
// Reference takes out[:, -1, :] = concat(h_fwd after T steps, h_bwd after ONE
// step from h0=0 on x[T-1]) -> only the forward scan is sequential; W_hh_b is
// entirely unused.
//
// R14: 16 lanes per row, 4 rows per wave, DPP-ONLY h all-gather.
//
// R13 post-mortem: ds_swizzle is DS-pipe (same latency class as ds_read) --
// the xor16 stage kept the DS round-trip on the chain and added issue
// (605 cyc/step, 377 issue).  R8's wall = 532 = ~350 compute + ~180 DS RT.
// Fix: shrink the gather domain to 16 lanes so EVERY stage is DPP
// (quad_perm l^1, l^2; row_half_mirror l^7; row_mirror l^15 -- VALU pipe,
// no lgkm, ~2 cyc issue each).  Each lane owns outputs (t, t+16) of its row
// packed as one h2; 15 DPP movs gather all 16 pairs in XOR slot order
// e = [0,1,2,3,7,6,5,4,15,14,13,12,8,9,10,11]; weights are loaded
// pre-permuted to match (slot s of lane t pairs cols t^e(s), t^e(s)+16).
// 4 rows share one instruction stream -> fixed overhead amortizes 2x better
// than R8, and the DS round-trip vanishes.  512 waves (1 wave on half the
// SIMDs) -- irrelevant: the wall is per-wave serial chain, not occupancy.
//
//   * Weights f16 packed, 6 gate-rows x 16 slots = 96 h2 VGPRs, pre-scaled
//     into exp2 domain (r/z by -log2e, n by 2log2e), pinned (budget 512 at
//     waves_per_eu(1,1)).
//   * h state fp32 x2 per lane; packed to h2 once per step (cvt+pack).
//   * sigmoid = v_rcp(1+v_exp2(.)), tanh = 1-2*v_rcp(1+v_exp2(.)).
//   * x staged in LDS (rows padded +4 floats -> the 4 groups' broadcast
//     ds_read_b128 hit disjoint bank quads), vf4 per 4 steps.
//   * Epilogue: backward single step + MLP head adapted to 16-lane groups.

typedef float vf4 __attribute__((ext_vector_type(4)));
typedef _Float16 f16;
typedef f16 h2 __attribute__((ext_vector_type(2)));

#define TT 512
#define HH 32

#define PIN(v) asm volatile("" : "+v"(v))

#define LOG2E 1.44269504f

__device__ __forceinline__ float fast_sigm(float a) {
  return __builtin_amdgcn_rcpf(1.0f + __builtin_amdgcn_exp2f(-LOG2E * a));
}
__device__ __forceinline__ float fast_tanh(float a) {
  return __builtin_fmaf(-2.0f,
      __builtin_amdgcn_rcpf(1.0f + __builtin_amdgcn_exp2f(2.0f * LOG2E * a)),
      1.0f);
}

template <int CTRL>
__device__ __forceinline__ int dpp(int v) {
  return __builtin_amdgcn_mov_dpp(v, CTRL, 0xF, 0xF, true);
}
#define DPP_X1 0xB1   // quad_perm(1,0,3,2): lane^1
#define DPP_X2 0x4E   // quad_perm(2,3,0,1): lane^2
#define DPP_HM 0x141  // row_half_mirror:    lane^7 (within 8)
#define DPP_M  0x140  // row_mirror:         lane^15 (within 16)

__device__ __forceinline__ h2 asH2(int v) { return __builtin_bit_cast(h2, v); }
__device__ __forceinline__ int asI(h2 v) { return __builtin_bit_cast(int, v); }

// weight slot: cols (t^e, t^e+16) of one gate row, pre-scaled, packed f16
__device__ __forceinline__ h2 wpair(const float* Wrow, int t, int e, float s) {
  const int c = t ^ e;
  h2 r = {(f16)(Wrow[c] * s), (f16)(Wrow[c + 16] * s)};
  return r;
}

// 16 slots for one gate row, in the DPP-tree's XOR slot order
#define LDWG(P, ROWPTR, S) \
  h2 P##0 = wpair(ROWPTR, t, 0, S),  P##1 = wpair(ROWPTR, t, 1, S), \
     P##2 = wpair(ROWPTR, t, 2, S),  P##3 = wpair(ROWPTR, t, 3, S), \
     P##4 = wpair(ROWPTR, t, 7, S),  P##5 = wpair(ROWPTR, t, 6, S), \
     P##6 = wpair(ROWPTR, t, 5, S),  P##7 = wpair(ROWPTR, t, 4, S), \
     P##8 = wpair(ROWPTR, t, 15, S), P##9 = wpair(ROWPTR, t, 14, S), \
     P##A = wpair(ROWPTR, t, 13, S), P##B = wpair(ROWPTR, t, 12, S), \
     P##C = wpair(ROWPTR, t, 8, S),  P##D = wpair(ROWPTR, t, 9, S), \
     P##E = wpair(ROWPTR, t, 10, S), P##F = wpair(ROWPTR, t, 11, S); \
  PIN(P##0);PIN(P##1);PIN(P##2);PIN(P##3);PIN(P##4);PIN(P##5);PIN(P##6);PIN(P##7); \
  PIN(P##8);PIN(P##9);PIN(P##A);PIN(P##B);PIN(P##C);PIN(P##D);PIN(P##E);PIN(P##F)

// 16 v_dot2 of slot values (y0..yF) . weights (P0..PF), 2 chains, A0 seeded
#define FDOT16(A0, A1, P, SEED) \
  float A0 = __builtin_amdgcn_fdot2(y0, P##0, (SEED), false); \
  float A1 = __builtin_amdgcn_fdot2(y1, P##1, 0.0f, false); \
  A0 = __builtin_amdgcn_fdot2(y2, P##2, A0, false);  A1 = __builtin_amdgcn_fdot2(y3, P##3, A1, false); \
  A0 = __builtin_amdgcn_fdot2(y4, P##4, A0, false);  A1 = __builtin_amdgcn_fdot2(y5, P##5, A1, false); \
  A0 = __builtin_amdgcn_fdot2(y6, P##6, A0, false);  A1 = __builtin_amdgcn_fdot2(y7, P##7, A1, false); \
  A0 = __builtin_amdgcn_fdot2(y8, P##8, A0, false);  A1 = __builtin_amdgcn_fdot2(y9, P##9, A1, false); \
  A0 = __builtin_amdgcn_fdot2(yA, P##A, A0, false);  A1 = __builtin_amdgcn_fdot2(yB, P##B, A1, false); \
  A0 = __builtin_amdgcn_fdot2(yC, P##C, A0, false);  A1 = __builtin_amdgcn_fdot2(yD, P##D, A1, false); \
  A0 = __builtin_amdgcn_fdot2(yE, P##E, A0, false);  A1 = __builtin_amdgcn_fdot2(yF, P##F, A1, false)

__global__ __launch_bounds__(128)
__attribute__((amdgpu_waves_per_eu(1, 1)))
void gru_bidir_head(const float* __restrict__ X,
                    const float* __restrict__ Wih_f, const float* __restrict__ Whh_f,
                    const float* __restrict__ bih_f, const float* __restrict__ bhh_f,
                    const float* __restrict__ Wih_b,
                    const float* __restrict__ bih_b, const float* __restrict__ bhh_b,
                    const float* __restrict__ W1, const float* __restrict__ b1,
                    const float* __restrict__ W2, const float* __restrict__ b2,
                    float* __restrict__ out)
{
  __shared__ float xbuf[8][TT + 4];    // +4 pad: groups hit disjoint bank quads
  __shared__ float obuf[8][64];        // [row][h_f(32) | h_b(32)]

  const int L    = threadIdx.x & 63;   // lane in wave
  const int w    = threadIdx.x >> 6;   // wave in block (0..1)
  const int rg   = L >> 4;             // row group in wave (0..3)
  const int t    = L & 15;             // lane in group; owns outputs t, t+16
  const int slot = (w << 2) + rg;      // row slot in block (0..7)
  const int b    = (blockIdx.x << 3) + slot;

  // --- stage this row of X into LDS (8 x vf4 per lane, coalesced) ---
  const vf4* Xr4 = (const vf4*)(X + (size_t)b * TT);
  vf4* xb4 = (vf4*)&xbuf[slot][0];
  #pragma unroll
  for (int q = 0; q < 8; ++q) xb4[t + 16 * q] = Xr4[t + 16 * q];
  __builtin_amdgcn_wave_barrier();

  // --- per-lane weights: 6 gate rows (r/z/n for outputs t and t+16),
  //     slot-permuted, exp2-domain pre-scaled, packed f16, pinned ---
  const float s1 = -LOG2E;             // r,z: sigmoid domain (negated)
  const float s2 = 2.0f * LOG2E;       // n: tanh domain
  LDWG(WrL, Whh_f + (size_t)(t)           * HH, s1);
  LDWG(WrH, Whh_f + (size_t)(t + 16)      * HH, s1);
  LDWG(WzL, Whh_f + (size_t)(HH + t)      * HH, s1);
  LDWG(WzH, Whh_f + (size_t)(HH + t + 16) * HH, s1);
  LDWG(WnL, Whh_f + (size_t)(2*HH + t)      * HH, s2);
  LDWG(WnH, Whh_f + (size_t)(2*HH + t + 16) * HH, s2);

  float xwrL = Wih_f[t] * s1,      xwrH = Wih_f[t + 16] * s1;
  float xwzL = Wih_f[HH + t] * s1, xwzH = Wih_f[HH + t + 16] * s1;
  float xwnL = Wih_f[2*HH + t] * s2, xwnH = Wih_f[2*HH + t + 16] * s2;
  float cbrL = (bih_f[t] + bhh_f[t]) * s1;
  float cbrH = (bih_f[t + 16] + bhh_f[t + 16]) * s1;
  float cbzL = (bih_f[HH + t] + bhh_f[HH + t]) * s1;
  float cbzH = (bih_f[HH + t + 16] + bhh_f[HH + t + 16]) * s1;
  float cbnL = bih_f[2*HH + t] * s2,      cbnH = bih_f[2*HH + t + 16] * s2;
  float cbhL = bhh_f[2*HH + t] * s2,      cbhH = bhh_f[2*HH + t + 16] * s2;
  PIN(xwrL); PIN(xwrH); PIN(xwzL); PIN(xwzH); PIN(xwnL); PIN(xwnH);
  PIN(cbrL); PIN(cbrH); PIN(cbzL); PIN(cbzH); PIN(cbnL); PIN(cbnH);
  PIN(cbhL); PIN(cbhH);

  float hL = 0.0f, hH = 0.0f;          // fp32 state for outputs t, t+16
  const vf4* xv = (const vf4*)&xbuf[slot][0];
  vf4 x4 = xv[0];

  #pragma unroll 1
  for (int tg = 0; tg < TT / 4; ++tg) {
    const vf4 x4n = xv[tg + 1 < TT / 4 ? tg + 1 : tg];   // off critical path

    // hoist x-terms for 4 sub-steps x 6 seeds
    float srL0 = __builtin_fmaf(x4.x, xwrL, cbrL), srH0 = __builtin_fmaf(x4.x, xwrH, cbrH);
    float szL0 = __builtin_fmaf(x4.x, xwzL, cbzL), szH0 = __builtin_fmaf(x4.x, xwzH, cbzH);
    float snL0 = __builtin_fmaf(x4.x, xwnL, cbnL), snH0 = __builtin_fmaf(x4.x, xwnH, cbnH);
    float srL1 = __builtin_fmaf(x4.y, xwrL, cbrL), srH1 = __builtin_fmaf(x4.y, xwrH, cbrH);
    float szL1 = __builtin_fmaf(x4.y, xwzL, cbzL), szH1 = __builtin_fmaf(x4.y, xwzH, cbzH);
    float snL1 = __builtin_fmaf(x4.y, xwnL, cbnL), snH1 = __builtin_fmaf(x4.y, xwnH, cbnH);
    float srL2 = __builtin_fmaf(x4.z, xwrL, cbrL), srH2 = __builtin_fmaf(x4.z, xwrH, cbrH);
    float szL2 = __builtin_fmaf(x4.z, xwzL, cbzL), szH2 = __builtin_fmaf(x4.z, xwzH, cbzH);
    float snL2 = __builtin_fmaf(x4.z, xwnL, cbnL), snH2 = __builtin_fmaf(x4.z, xwnH, cbnH);
    float srL3 = __builtin_fmaf(x4.w, xwrL, cbrL), srH3 = __builtin_fmaf(x4.w, xwrH, cbrH);
    float szL3 = __builtin_fmaf(x4.w, xwzL, cbzL), szH3 = __builtin_fmaf(x4.w, xwzH, cbzH);
    float snL3 = __builtin_fmaf(x4.w, xwnL, cbnL), snH3 = __builtin_fmaf(x4.w, xwnH, cbnH);

    #pragma unroll
    for (int u = 0; u < 4; ++u) {
      const float srL = (u==0)?srL0:(u==1)?srL1:(u==2)?srL2:srL3;
      const float srH = (u==0)?srH0:(u==1)?srH1:(u==2)?srH2:srH3;
      const float szL = (u==0)?szL0:(u==1)?szL1:(u==2)?szL2:szL3;
      const float szH = (u==0)?szH0:(u==1)?szH1:(u==2)?szH2:szH3;
      const float snL = (u==0)?snL0:(u==1)?snL1:(u==2)?snL2:snL3;
      const float snH = (u==0)?snH0:(u==1)?snH1:(u==2)?snH2:snH3;

      // ---- DPP-only all-gather of the group's 16 h-pairs (no DS!) ----
      const h2 hp = {(f16)hL, (f16)hH};
      const int p0 = asI(hp);                  // e=0
      const int p1 = dpp<DPP_X1>(p0);          // e=1
      const int p2 = dpp<DPP_X2>(p0);          // e=2
      const int p3 = dpp<DPP_X2>(p1);          // e=3
      const int p4 = dpp<DPP_HM>(p0);          // e=7
      const int p5 = dpp<DPP_HM>(p1);          // e=6
      const int p6 = dpp<DPP_HM>(p2);          // e=5
      const int p7 = dpp<DPP_HM>(p3);          // e=4
      const int p8 = dpp<DPP_M>(p0);           // e=15
      const int p9 = dpp<DPP_M>(p1);           // e=14
      const int pA = dpp<DPP_M>(p2);           // e=13
      const int pB = dpp<DPP_M>(p3);           // e=12
      const int pC = dpp<DPP_M>(p4);           // e=8
      const int pD = dpp<DPP_M>(p5);           // e=9
      const int pE = dpp<DPP_M>(p6);           // e=10
      const int pF = dpp<DPP_M>(p7);           // e=11

      const h2 y0 = asH2(p0), y1 = asH2(p1), y2 = asH2(p2), y3 = asH2(p3),
               y4 = asH2(p4), y5 = asH2(p5), y6 = asH2(p6), y7 = asH2(p7),
               y8 = asH2(p8), y9 = asH2(p9), yA = asH2(pA), yB = asH2(pB),
               yC = asH2(pC), yD = asH2(pD), yE = asH2(pE), yF = asH2(pF);

      FDOT16(RaL, RbL, WrL, srL);
      FDOT16(ZaL, ZbL, WzL, szL);
      FDOT16(NaL, NbL, WnL, cbhL);
      FDOT16(RaH, RbH, WrH, srH);
      FDOT16(ZaH, ZbH, WzH, szH);
      FDOT16(NaH, NbH, WnH, cbhH);

      const float rL = __builtin_amdgcn_rcpf(1.0f + __builtin_amdgcn_exp2f(RaL + RbL));
      const float zL = __builtin_amdgcn_rcpf(1.0f + __builtin_amdgcn_exp2f(ZaL + ZbL));
      const float yLv = __builtin_fmaf(rL, NaL + NbL, snL);
      const float nL = __builtin_fmaf(-2.0f,
          __builtin_amdgcn_rcpf(1.0f + __builtin_amdgcn_exp2f(yLv)), 1.0f);
      hL = __builtin_fmaf(zL, hL - nL, nL);

      const float rH = __builtin_amdgcn_rcpf(1.0f + __builtin_amdgcn_exp2f(RaH + RbH));
      const float zH = __builtin_amdgcn_rcpf(1.0f + __builtin_amdgcn_exp2f(ZaH + ZbH));
      const float yHv = __builtin_fmaf(rH, NaH + NbH, snH);
      const float nH = __builtin_fmaf(-2.0f,
          __builtin_amdgcn_rcpf(1.0f + __builtin_amdgcn_exp2f(yHv)), 1.0f);
      hH = __builtin_fmaf(zH, hH - nH, nH);
    }
    x4 = x4n;
  }

  // --- backward direction: exactly ONE GRU step from h0=0 on x[T-1] ---
  const float xl = xbuf[slot][TT - 1];
  float hbL, hbH;
  {
    const float rb  = fast_sigm(__builtin_fmaf(xl, Wih_b[t],      bih_b[t]      + bhh_b[t]));
    const float zb  = fast_sigm(__builtin_fmaf(xl, Wih_b[HH + t], bih_b[HH + t] + bhh_b[HH + t]));
    const float xnb = __builtin_fmaf(xl, Wih_b[2*HH + t], bih_b[2*HH + t]);
    const float nb_ = fast_tanh(__builtin_fmaf(rb, bhh_b[2*HH + t], xnb));
    hbL = nb_ - zb * nb_;
  }
  {
    const int i = t + 16;
    const float rb  = fast_sigm(__builtin_fmaf(xl, Wih_b[i],      bih_b[i]      + bhh_b[i]));
    const float zb  = fast_sigm(__builtin_fmaf(xl, Wih_b[HH + i], bih_b[HH + i] + bhh_b[HH + i]));
    const float xnb = __builtin_fmaf(xl, Wih_b[2*HH + i], bih_b[2*HH + i]);
    const float nb_ = fast_tanh(__builtin_fmaf(rb, bhh_b[2*HH + i], xnb));
    hbH = nb_ - zb * nb_;
  }

  obuf[slot][t]        = hL;           // h_f[t]
  obuf[slot][t + 16]   = hH;           // h_f[t+16]
  obuf[slot][32 + t]   = hbL;          // h_b[t]
  obuf[slot][48 + t]   = hbH;          // h_b[t+16]
  __builtin_amdgcn_wave_barrier();

  // --- MLP head: sigmoid(W2 @ relu(W1 @ [h_f,h_b] + b1) + b2) ---
  // 16 lanes per row group: lane t computes hidden unit t.
  const vf4* W1r = (const vf4*)(W1 + t * 64);
  const vf4* hc  = (const vf4*)&obuf[slot][0];
  vf4 a4 = W1r[0] * hc[0];
  #pragma unroll
  for (int q = 1; q < 16; ++q)
    a4 = __builtin_elementwise_fma(W1r[q], hc[q], a4);
  float acc = b1[t] + (a4.x + a4.y) + (a4.z + a4.w);
  float h1 = fmaxf(acc, 0.0f) * W2[t];
  h1 += __shfl_down(h1, 8, 16);
  h1 += __shfl_down(h1, 4, 16);
  h1 += __shfl_down(h1, 2, 16);
  h1 += __shfl_down(h1, 1, 16);
  if (t == 0) out[b] = fast_sigm(h1 + b2[0]);
}

extern "C" void kernel_launch(void* const* d_in, const int* in_sizes, int n_in,
                              void* d_out, int out_size, void* d_ws, size_t ws_size,
                              hipStream_t stream) {
  const float* X     = (const float*)d_in[0];
  const float* Wih_f = (const float*)d_in[1];
  const float* Whh_f = (const float*)d_in[2];
  const float* bih_f = (const float*)d_in[3];
  const float* bhh_f = (const float*)d_in[4];
  const float* Wih_b = (const float*)d_in[5];
  // d_in[6] = W_hh_b: unused — backward direction runs exactly one step from h0=0.
  const float* bih_b = (const float*)d_in[7];
  const float* bhh_b = (const float*)d_in[8];
  const float* W1    = (const float*)d_in[9];
  const float* b1    = (const float*)d_in[10];
  const float* W2    = (const float*)d_in[11];
  const float* b2    = (const float*)d_in[12];
  float* out = (float*)d_out;

  // 2048 rows / (4 rows per wave x 2 waves per 128-thread block) = 256 blocks
  // = 1 block/CU; 512 waves total (wall is per-wave serial, not occupancy).
  gru_bidir_head<<<256, 128, 0, stream>>>(X, Wih_f, Whh_f, bih_f, bhh_f,
                                          Wih_b, bih_b, bhh_b, W1, b1, W2, b2, out);
}

// Round 15
// 178.391 us; speedup vs baseline: 1.3019x; 1.3019x over previous
//
#include <hip/hip_runtime.h>

// Bidirectional GRU (H=32, input=1, B=2048, T=512) + MLP head, fully fused.
//
// Reference takes out[:, -1, :] = concat(h_fwd after T steps, h_bwd after ONE
// step from h0=0 on x[T-1]) -> only the forward scan is sequential; W_hh_b is
// entirely unused.
//
// R15: hybrid h-gather = DPP (own 16-half, no DS) + LDS (other 16-half).
//
// Wall model (R8..R14 measured): R8's 532 cyc/step = ~150 RT dead-time
// (after ds_write, dots all wait on ds_read; nothing to issue) + ~192 dot
// issue + ~190 tail/misc.  Multi-row/multi-wave variants all lose because
// waves issue instructions, not lanes (wall = 512 x per-wave step).  The fix
// that adds ZERO issue: a lane's own 16-half of h never needs LDS -- R14's
// 15-DPP tree (quad_perm l^1/l^2, row_half_mirror l^7, row_mirror l^15)
// stays inside each 16-lane half.  Only the opposite half goes through LDS.
// Schedule: write h -> issue 2x ds_read_b128 (other half) -> DPP tree + 24
// own-half dot2 ISSUE DURING THE READ FLIGHT -> waitcnt (mostly drained) ->
// 24 other-half dot2 -> gates tail.  Predicted step ~450 cyc vs 532.
//
//   * 32 lanes/row (lane-efficient), 2 rows/wave as half-waves, 256 blocks
//     x 256 thr = 1024 waves = 1 wave/SIMD.
//   * Own-half weights slot-permuted to the DPP tree's XOR order
//     e = [(0,1)(2,3)(7,6)(5,4)(15,14)(13,12)(8,9)(10,11)] on t = g&15,
//     absolute col = 16*H + (t^e); other-half weights linear from 16*(1-H).
//   * f16 dot2 w/ f32 accumulate; 48 h2 weights + 7 bias scalars pinned
//     (fits the proven 132-reg envelope; R8-equal footprint).
//   * exp2-domain gates: sigmoid = v_rcp(1+v_exp2(.)),
//     tanh = 1-2*v_rcp(1+v_exp2(.)).
//   * x staged in LDS f32, vf4 per 4 steps.

typedef float vf4 __attribute__((ext_vector_type(4)));
typedef _Float16 f16;
typedef f16 h2 __attribute__((ext_vector_type(2)));
typedef f16 h8 __attribute__((ext_vector_type(8)));

#define TT 512
#define HH 32

#define PIN(v) asm volatile("" : "+v"(v))

#define LOG2E 1.44269504f

__device__ __forceinline__ float fast_sigm(float a) {
  return __builtin_amdgcn_rcpf(1.0f + __builtin_amdgcn_exp2f(-LOG2E * a));
}
__device__ __forceinline__ float fast_tanh(float a) {
  return __builtin_fmaf(-2.0f,
      __builtin_amdgcn_rcpf(1.0f + __builtin_amdgcn_exp2f(2.0f * LOG2E * a)),
      1.0f);
}

template <int CTRL>
__device__ __forceinline__ int dpp(int v) {
  return __builtin_amdgcn_mov_dpp(v, CTRL, 0xF, 0xF, true);
}
#define DPP_X1 0xB1   // quad_perm(1,0,3,2): lane^1
#define DPP_X2 0x4E   // quad_perm(2,3,0,1): lane^2
#define DPP_HM 0x141  // row_half_mirror:    lane^7 (within 8)
#define DPP_M  0x140  // row_mirror:         lane^15 (within 16)

__device__ __forceinline__ h2 asH2(int v) { return __builtin_bit_cast(h2, v); }
__device__ __forceinline__ int asI(h2 v) { return __builtin_bit_cast(int, v); }

// own-half weight slot: within-half cols (t^e0, t^e1), pre-scaled, f16
__device__ __forceinline__ h2 wpair(const float* base, int t, int e0, int e1,
                                    float s) {
  h2 r = {(f16)(base[t ^ e0] * s), (f16)(base[t ^ e1] * s)};
  return r;
}
// other-half weight slot k: cols (2k, 2k+1) of the opposite half
__device__ __forceinline__ h2 wlin(const float* base, int k, float s) {
  h2 r = {(f16)(base[2 * k] * s), (f16)(base[2 * k + 1] * s)};
  return r;
}

// 8 own-half slots (DPP XOR order) — base points at this half's 16 cols
#define LDWO(P, BASE, S) \
  h2 P##0 = wpair(BASE, t, 0, 1, S),   P##1 = wpair(BASE, t, 2, 3, S), \
     P##2 = wpair(BASE, t, 7, 6, S),   P##3 = wpair(BASE, t, 5, 4, S), \
     P##4 = wpair(BASE, t, 15, 14, S), P##5 = wpair(BASE, t, 13, 12, S), \
     P##6 = wpair(BASE, t, 8, 9, S),   P##7 = wpair(BASE, t, 10, 11, S); \
  PIN(P##0);PIN(P##1);PIN(P##2);PIN(P##3);PIN(P##4);PIN(P##5);PIN(P##6);PIN(P##7)

// 8 other-half slots (linear) — base points at the opposite half's 16 cols
#define LDWL(P, BASE, S) \
  h2 P##0 = wlin(BASE, 0, S), P##1 = wlin(BASE, 1, S), \
     P##2 = wlin(BASE, 2, S), P##3 = wlin(BASE, 3, S), \
     P##4 = wlin(BASE, 4, S), P##5 = wlin(BASE, 5, S), \
     P##6 = wlin(BASE, 6, S), P##7 = wlin(BASE, 7, S); \
  PIN(P##0);PIN(P##1);PIN(P##2);PIN(P##3);PIN(P##4);PIN(P##5);PIN(P##6);PIN(P##7)

// 8-dot2 chain over own-half slots y0..y7 (issueable during read flight)
#define DOT8Y(ACC, P, SEED) \
  float ACC = __builtin_amdgcn_fdot2(y0, P##0, (SEED), false); \
  ACC = __builtin_amdgcn_fdot2(y1, P##1, ACC, false); \
  ACC = __builtin_amdgcn_fdot2(y2, P##2, ACC, false); \
  ACC = __builtin_amdgcn_fdot2(y3, P##3, ACC, false); \
  ACC = __builtin_amdgcn_fdot2(y4, P##4, ACC, false); \
  ACC = __builtin_amdgcn_fdot2(y5, P##5, ACC, false); \
  ACC = __builtin_amdgcn_fdot2(y6, P##6, ACC, false); \
  ACC = __builtin_amdgcn_fdot2(y7, P##7, ACC, false)

// 8-dot2 chain over LDS-half slots u0..u7 (first use of the ds_read data)
#define DOT8U(ACC, P) \
  float ACC = __builtin_amdgcn_fdot2(u0, P##0, 0.0f, false); \
  ACC = __builtin_amdgcn_fdot2(u1, P##1, ACC, false); \
  ACC = __builtin_amdgcn_fdot2(u2, P##2, ACC, false); \
  ACC = __builtin_amdgcn_fdot2(u3, P##3, ACC, false); \
  ACC = __builtin_amdgcn_fdot2(u4, P##4, ACC, false); \
  ACC = __builtin_amdgcn_fdot2(u5, P##5, ACC, false); \
  ACC = __builtin_amdgcn_fdot2(u6, P##6, ACC, false); \
  ACC = __builtin_amdgcn_fdot2(u7, P##7, ACC, false)

__global__ __launch_bounds__(256)
__attribute__((amdgpu_waves_per_eu(1, 1)))
void gru_bidir_head(const float* __restrict__ X,
                    const float* __restrict__ Wih_f, const float* __restrict__ Whh_f,
                    const float* __restrict__ bih_f, const float* __restrict__ bhh_f,
                    const float* __restrict__ Wih_b,
                    const float* __restrict__ bih_b, const float* __restrict__ bhh_b,
                    const float* __restrict__ W1, const float* __restrict__ b1,
                    const float* __restrict__ W2, const float* __restrict__ b2,
                    float* __restrict__ out)
{
  __shared__ float xbuf[8][TT];        // staged input rows (16 KB)
  __shared__ f16   hbuf[8][HH];        // h broadcast, f16 (512 B)
  __shared__ float obuf[8][64];        // [row][h_f(32) | h_b(32)] (2 KB)

  const int g  = threadIdx.x & 31;     // lane within row group = output index
  const int rs = threadIdx.x >> 5;     // row slot in block (0..7)
  const int b  = (blockIdx.x << 3) + rs;
  const int H  = g >> 4;               // which 16-half this lane is in
  const int t  = g & 15;               // lane within its half

  // --- stage this row of X into LDS (4 x vf4 per lane, coalesced) ---
  const vf4* Xr4 = (const vf4*)(X + (size_t)b * TT);
  vf4* xb4 = (vf4*)&xbuf[rs][0];
  #pragma unroll
  for (int q = 0; q < 4; ++q) xb4[g + 32 * q] = Xr4[g + 32 * q];

  // --- per-lane weights: gate rows g, 32+g, 64+g; own half DPP-permuted,
  //     other half linear; exp2-domain pre-scaled; packed f16; pinned ---
  const float s1 = -LOG2E;             // r,z: sigmoid domain (negated)
  const float s2 = 2.0f * LOG2E;       // n: tanh domain
  const float* Wr_row = Whh_f + (size_t)(g)        * HH;
  const float* Wz_row = Whh_f + (size_t)(HH + g)   * HH;
  const float* Wn_row = Whh_f + (size_t)(2*HH + g) * HH;
  const int own = 16 * H, oth = 16 * (1 - H);
  LDWO(WrO, Wr_row + own, s1);
  LDWO(WzO, Wz_row + own, s1);
  LDWO(WnO, Wn_row + own, s2);
  LDWL(WrL, Wr_row + oth, s1);
  LDWL(WzL, Wz_row + oth, s1);
  LDWL(WnL, Wn_row + oth, s2);

  float xwr = Wih_f[g] * s1, xwz = Wih_f[HH + g] * s1, xwn = Wih_f[2*HH + g] * s2;
  float cbr = (bih_f[g]      + bhh_f[g])      * s1;
  float cbz = (bih_f[HH + g] + bhh_f[HH + g]) * s1;
  float cbn = bih_f[2*HH + g] * s2;            // n: b_ih term (with x)
  float cbh = bhh_f[2*HH + g] * s2;            // n: b_hh term (inside r*(...))
  PIN(xwr); PIN(xwz); PIN(xwn); PIN(cbr); PIN(cbz); PIN(cbn); PIN(cbh);

  float h = 0.0f;
  hbuf[rs][g] = (f16)0.0f;
  __builtin_amdgcn_wave_barrier();

  const h8*  hvO = (const h8*)&hbuf[rs][oth];  // opposite half: 2 x b128
  const vf4* xv  = (const vf4*)&xbuf[rs][0];
  vf4 x4 = xv[0];

  #pragma unroll 1
  for (int tg = 0; tg < TT / 4; ++tg) {
    const vf4 x4n = xv[tg + 1 < TT / 4 ? tg + 1 : tg];   // off critical path
    #pragma unroll
    for (int u = 0; u < 4; ++u) {
      const float x = (u == 0) ? x4.x : (u == 1) ? x4.y : (u == 2) ? x4.z : x4.w;

      // 1) read the OPPOSITE half of h (written end of previous step /
      //    pre-loop init).  DS is in-order per wave; wave_barrier at the
      //    end of the previous step pins compiler ordering.
      const h8 O0 = hvO[0], O1 = hvO[1];

      // 2) DPP all-gather of OWN half from register h (no DS, ~4cyc each)
      const f16 hf = (f16)h;
      const h2 self = {hf, hf};
      const int nb = dpp<DPP_X1>(asI(self));
      const h2 pr = {self[0], asH2(nb)[0]};    // (t, t^1)
      const int p0 = asI(pr);
      const int p1 = dpp<DPP_X2>(p0);          // (t^2, t^3)
      const int p2 = dpp<DPP_HM>(p0);          // (t^7, t^6)
      const int p3 = dpp<DPP_HM>(p1);          // (t^5, t^4)
      const int p4 = dpp<DPP_M>(p0);           // (t^15, t^14)
      const int p5 = dpp<DPP_M>(p1);           // (t^13, t^12)
      const int p6 = dpp<DPP_M>(p2);           // (t^8, t^9)
      const int p7 = dpp<DPP_M>(p3);           // (t^10, t^11)
      const h2 y0 = asH2(p0), y1 = asH2(p1), y2 = asH2(p2), y3 = asH2(p3),
               y4 = asH2(p4), y5 = asH2(p5), y6 = asH2(p6), y7 = asH2(p7);

      // 3) own-half dots: 24 dot2 issue WHILE the 2 ds_reads are in flight
      DOT8Y(Ro, WrO, __builtin_fmaf(x, xwr, cbr));
      DOT8Y(Zo, WzO, __builtin_fmaf(x, xwz, cbz));
      DOT8Y(No, WnO, cbh);

      // 4) other-half dots (first use of O0/O1 -> waitcnt lands here, mostly
      //    drained by the ~130 cyc of DPP+own-dot issue above)
      const h2 u0 = {O0[0], O0[1]}, u1 = {O0[2], O0[3]},
               u2 = {O0[4], O0[5]}, u3 = {O0[6], O0[7]},
               u4 = {O1[0], O1[1]}, u5 = {O1[2], O1[3]},
               u6 = {O1[4], O1[5]}, u7 = {O1[6], O1[7]};
      DOT8U(Rl, WrL);
      DOT8U(Zl, WzL);
      DOT8U(Nl, WnL);

      // 5) gates tail (exp2 domain)
      const float ar = Ro + Rl;
      const float az = Zo + Zl;
      const float r = __builtin_amdgcn_rcpf(1.0f + __builtin_amdgcn_exp2f(ar));
      const float z = __builtin_amdgcn_rcpf(1.0f + __builtin_amdgcn_exp2f(az));
      const float y = __builtin_fmaf(r, No + Nl, __builtin_fmaf(x, xwn, cbn));
      const float n = __builtin_fmaf(-2.0f,
          __builtin_amdgcn_rcpf(1.0f + __builtin_amdgcn_exp2f(y)), 1.0f);
      h = __builtin_fmaf(z, h - n, n);           // (1-z)*n + z*h

      // 6) publish h for the other half's NEXT step; barrier pins ordering
      hbuf[rs][g] = (f16)h;
      __builtin_amdgcn_wave_barrier();
    }
    x4 = x4n;
  }

  // --- backward direction: exactly ONE GRU step from h0=0 on x[T-1] ---
  const float xl  = xbuf[rs][TT - 1];
  const float rb  = fast_sigm(__builtin_fmaf(xl, Wih_b[g],      bih_b[g]      + bhh_b[g]));
  const float zb  = fast_sigm(__builtin_fmaf(xl, Wih_b[HH + g], bih_b[HH + g] + bhh_b[HH + g]));
  const float xnb = __builtin_fmaf(xl, Wih_b[2*HH + g], bih_b[2*HH + g]);
  const float nb_ = fast_tanh(__builtin_fmaf(rb, bhh_b[2*HH + g], xnb));
  const float hb  = nb_ - zb * nb_;              // (1-zb)*nb + zb*0

  obuf[rs][g]      = h;                          // h_f (full fp32 state)
  obuf[rs][32 + g] = hb;                         // h_b
  __builtin_amdgcn_wave_barrier();

  // --- MLP head: sigmoid(W2 @ relu(W1 @ [h_f,h_b] + b1) + b2) ---
  const int j = g & 15;                          // lanes 16..31 duplicate
  const vf4* W1r = (const vf4*)(W1 + j * 64);
  const vf4* hc  = (const vf4*)&obuf[rs][0];
  vf4 a4 = W1r[0] * hc[0];
  #pragma unroll
  for (int q = 1; q < 16; ++q)
    a4 = __builtin_elementwise_fma(W1r[q], hc[q], a4);
  float acc = b1[j] + (a4.x + a4.y) + (a4.z + a4.w);
  float h1 = fmaxf(acc, 0.0f) * W2[j];
  h1 += __shfl_down(h1, 8, 16);
  h1 += __shfl_down(h1, 4, 16);
  h1 += __shfl_down(h1, 2, 16);
  h1 += __shfl_down(h1, 1, 16);
  if (g == 0) out[b] = fast_sigm(h1 + b2[0]);
}

extern "C" void kernel_launch(void* const* d_in, const int* in_sizes, int n_in,
                              void* d_out, int out_size, void* d_ws, size_t ws_size,
                              hipStream_t stream) {
  const float* X     = (const float*)d_in[0];
  const float* Wih_f = (const float*)d_in[1];
  const float* Whh_f = (const float*)d_in[2];
  const float* bih_f = (const float*)d_in[3];
  const float* bhh_f = (const float*)d_in[4];
  const float* Wih_b = (const float*)d_in[5];
  // d_in[6] = W_hh_b: unused — backward direction runs exactly one step from h0=0.
  const float* bih_b = (const float*)d_in[7];
  const float* bhh_b = (const float*)d_in[8];
  const float* W1    = (const float*)d_in[9];
  const float* b1    = (const float*)d_in[10];
  const float* W2    = (const float*)d_in[11];
  const float* b2    = (const float*)d_in[12];
  float* out = (float*)d_out;

  // 2048 rows / 8 rows per 256-thread block = 256 blocks = 1 block/CU,
  // 1024 waves = 1 wave/SIMD (2 rows per wave as half-waves).
  gru_bidir_head<<<256, 256, 0, stream>>>(X, Wih_f, Whh_f, bih_f, bhh_f,
                                          Wih_b, bih_b, bhh_b, W1, b1, W2, b2, out);
}

// Round 16
// 177.098 us; speedup vs baseline: 1.3114x; 1.0073x over previous
//
#include <hip/hip_runtime.h>

// Bidirectional GRU (H=32, input=1, B=2048, T=512) + MLP head, fully fused.
//
// Reference takes out[:, -1, :] = concat(h_fwd after T steps, h_bwd after ONE
// step from h0=0 on x[T-1]) -> only the forward scan is sequential; W_hh_b is
// entirely unused.
//
// R16 = restore R8 (best measured: 113.5 us, 532 cyc/step), final state.
//
// CEILING MODEL (closed by R8-R15 measurements):
//   wall = 512 sequential steps x T_step (recurrence; confirmed by all
//   decompositions).  Per-row issue is invariant at ~163 cyc/row/step
//   (R8 full-dot 325/2rows; R9 K-split worse via shfl tax; R10 row-dup 2x
//   issue; R14 4-row 2x issue + spill).  2048 rows / 2 rows per wave =
//   1024 waves = exactly 1 wave/SIMD -> no co-resident wave can hide
//   latency without raising T_step more than it hides (measured thrice).
//   The per-step h-exchange costs ~150-190 cyc by ANY mechanism: LDS RT
//   (R8), ds_swizzle (R13: DS-pipe, worse), DPP+LDS hybrid (R15: neutral,
//   issue(+40) == stall(-40)); ~160 cyc has no independent work to overlap
//   (all downstream ops depend on the just-computed h).
//   Floor = issue(325) + unhidable exchange(~160) ~= 485-530 cyc/step.
//   R8 measures 532 -> within ~5% of the structural floor.  What would
//   change it: a sub-40-cyc cross-lane broadcast primitive, or a batch
//   large enough for 2 waves/SIMD at 2 rows/wave (needs B >= 4096).
//
// Structure:
//   * 32 lanes per row, full 32-wide f16 dot2 per lane, no shfl; 2 rows per
//     wave as half-waves; 256 blocks x 256 thr = 1024 waves = 1 wave/SIMD.
//   * Weights f16 packed (16 h2 per gate = 48 VGPRs), pre-scaled into exp2
//     domain (r/z by -log2e, n by 2log2e), pinned via inline-asm "+v"
//     (PIN beats rematerialization; amdgpu_waves_per_eu(1,1) gives the
//     512-reg budget so nothing spills -- the R1-R7 saga).
//   * h state fp32 per lane; broadcast copy f16 via ds_write_b16 + 4x
//     broadcast ds_read_b128 (conflict-free).
//   * exp2-domain gates: sigmoid = v_rcp(1+v_exp2(.)),
//     tanh = 1-2*v_rcp(1+v_exp2(.)).
//   * x staged in LDS f32, consumed as vf4 per 4 steps (prefetched).

typedef float vf2 __attribute__((ext_vector_type(2)));
typedef float vf4 __attribute__((ext_vector_type(4)));
typedef _Float16 f16;
typedef f16 h2 __attribute__((ext_vector_type(2)));
typedef f16 h8 __attribute__((ext_vector_type(8)));

#define TT 512
#define HH 32

// inline-asm defs are not rematerializable: forces a real VGPR def here.
#define PIN(v) asm volatile("" : "+v"(v))

#define LOG2E 1.44269504f

__device__ __forceinline__ float fast_sigm(float a) {   // sigmoid(a)
  return __builtin_amdgcn_rcpf(1.0f + __builtin_amdgcn_exp2f(-LOG2E * a));
}
__device__ __forceinline__ float fast_tanh(float a) {   // tanh(a)
  return __builtin_fmaf(-2.0f,
      __builtin_amdgcn_rcpf(1.0f + __builtin_amdgcn_exp2f(2.0f * LOG2E * a)),
      1.0f);
}

__device__ __forceinline__ h2 pack_h2(vf2 a, float s) {
  h2 r = {(f16)(a.x * s), (f16)(a.y * s)};
  return r;
}

// load one 32-float W_hh row as 16 packed-f16 h2 regs, pre-scaled, pinned
#define LDW16(P, BASE, S) \
  h2 P##0=pack_h2(Wp[(BASE)+0],(S)),  P##1=pack_h2(Wp[(BASE)+1],(S)), \
     P##2=pack_h2(Wp[(BASE)+2],(S)),  P##3=pack_h2(Wp[(BASE)+3],(S)), \
     P##4=pack_h2(Wp[(BASE)+4],(S)),  P##5=pack_h2(Wp[(BASE)+5],(S)), \
     P##6=pack_h2(Wp[(BASE)+6],(S)),  P##7=pack_h2(Wp[(BASE)+7],(S)), \
     P##8=pack_h2(Wp[(BASE)+8],(S)),  P##9=pack_h2(Wp[(BASE)+9],(S)), \
     P##A=pack_h2(Wp[(BASE)+10],(S)), P##B=pack_h2(Wp[(BASE)+11],(S)), \
     P##C=pack_h2(Wp[(BASE)+12],(S)), P##D=pack_h2(Wp[(BASE)+13],(S)), \
     P##E=pack_h2(Wp[(BASE)+14],(S)), P##F=pack_h2(Wp[(BASE)+15],(S)); \
  PIN(P##0);PIN(P##1);PIN(P##2);PIN(P##3);PIN(P##4);PIN(P##5);PIN(P##6);PIN(P##7); \
  PIN(P##8);PIN(P##9);PIN(P##A);PIN(P##B);PIN(P##C);PIN(P##D);PIN(P##E);PIN(P##F)

// 16 v_dot2_f32_f16 of (q0..qF).(P0..PF) into two chains A0,A1; A0 seeded.
#define FDOT16(A0, A1, P, SEED) \
  float A0 = __builtin_amdgcn_fdot2(q0, P##0, (SEED), false); \
  float A1 = __builtin_amdgcn_fdot2(q1, P##1, 0.0f, false); \
  A0 = __builtin_amdgcn_fdot2(q2, P##2, A0, false);  A1 = __builtin_amdgcn_fdot2(q3, P##3, A1, false); \
  A0 = __builtin_amdgcn_fdot2(q4, P##4, A0, false);  A1 = __builtin_amdgcn_fdot2(q5, P##5, A1, false); \
  A0 = __builtin_amdgcn_fdot2(q6, P##6, A0, false);  A1 = __builtin_amdgcn_fdot2(q7, P##7, A1, false); \
  A0 = __builtin_amdgcn_fdot2(q8, P##8, A0, false);  A1 = __builtin_amdgcn_fdot2(q9, P##9, A1, false); \
  A0 = __builtin_amdgcn_fdot2(qA, P##A, A0, false);  A1 = __builtin_amdgcn_fdot2(qB, P##B, A1, false); \
  A0 = __builtin_amdgcn_fdot2(qC, P##C, A0, false);  A1 = __builtin_amdgcn_fdot2(qD, P##D, A1, false); \
  A0 = __builtin_amdgcn_fdot2(qE, P##E, A0, false);  A1 = __builtin_amdgcn_fdot2(qF, P##F, A1, false)

__global__ __launch_bounds__(256)
__attribute__((amdgpu_waves_per_eu(1, 1)))
void gru_bidir_head(const float* __restrict__ X,
                    const float* __restrict__ Wih_f, const float* __restrict__ Whh_f,
                    const float* __restrict__ bih_f, const float* __restrict__ bhh_f,
                    const float* __restrict__ Wih_b,
                    const float* __restrict__ bih_b, const float* __restrict__ bhh_b,
                    const float* __restrict__ W1, const float* __restrict__ b1,
                    const float* __restrict__ W2, const float* __restrict__ b2,
                    float* __restrict__ out)
{
  __shared__ float xbuf[8][TT];        // staged input rows (16 KB)
  __shared__ f16   hbuf[8][HH];        // h broadcast, f16 (512 B)
  __shared__ float obuf[8][64];        // [row][h_f(32) | h_b(32)] (2 KB)

  const int g  = threadIdx.x & 31;     // lane within row group = output index i
  const int rs = threadIdx.x >> 5;     // row slot in block (0..7)
  const int b  = (blockIdx.x << 3) + rs;

  // --- stage this row of X into LDS (4 x vf4 per lane, coalesced) ---
  const vf4* Xr4 = (const vf4*)(X + (size_t)b * TT);
  vf4* xb4 = (vf4*)&xbuf[rs][0];
  #pragma unroll
  for (int q = 0; q < 4; ++q) xb4[g + 32 * q] = Xr4[g + 32 * q];

  // --- per-lane weights: W_hh rows g (r), 32+g (z), 64+g (n); pre-scaled,
  //     packed to f16, pinned (48 VGPRs total) ---
  const vf2* Wp = (const vf2*)Whh_f;   // row stride = 16 vf2
  const float s1 = -LOG2E;             // r,z: sigmoid in exp2 domain, negated
  const float s2 = 2.0f * LOG2E;       // n: tanh in exp2 domain
  LDW16(Wr, g * 16, s1);
  LDW16(Wz, (HH + g) * 16, s1);
  LDW16(Wn, (2 * HH + g) * 16, s2);

  float xwr = Wih_f[g] * s1, xwz = Wih_f[HH + g] * s1, xwn = Wih_f[2*HH + g] * s2;
  float cbr = (bih_f[g]      + bhh_f[g])      * s1;
  float cbz = (bih_f[HH + g] + bhh_f[HH + g]) * s1;
  float cbn = bih_f[2*HH + g] * s2;            // n: b_ih term (with x)
  float cbh = bhh_f[2*HH + g] * s2;            // n: b_hh term (inside r*(...))
  PIN(xwr); PIN(xwz); PIN(xwn); PIN(cbr); PIN(cbz); PIN(cbn); PIN(cbh);

  float h = 0.0f;
  hbuf[rs][g] = (f16)0.0f;
  __builtin_amdgcn_wave_barrier();

  const h8*  hv = (const h8*)&hbuf[rs][0];     // 4 x b128 = all 32 f16 h
  const vf4* xv = (const vf4*)&xbuf[rs][0];
  vf4 x4 = xv[0];

  #pragma unroll 1
  for (int tg = 0; tg < TT / 4; ++tg) {
    const vf4 x4n = xv[tg + 1 < TT / 4 ? tg + 1 : tg];   // off critical path
    #pragma unroll
    for (int u = 0; u < 4; ++u) {
      const float x = (u == 0) ? x4.x : (u == 1) ? x4.y : (u == 2) ? x4.z : x4.w;

      // all 32 h (f16): 4 broadcast ds_read_b128
      h8 H0 = hv[0], H1 = hv[1], H2 = hv[2], H3 = hv[3];
      h2 q0 = {H0[0], H0[1]}, q1 = {H0[2], H0[3]}, q2 = {H0[4], H0[5]}, q3 = {H0[6], H0[7]},
         q4 = {H1[0], H1[1]}, q5 = {H1[2], H1[3]}, q6 = {H1[4], H1[5]}, q7 = {H1[6], H1[7]},
         q8 = {H2[0], H2[1]}, q9 = {H2[2], H2[3]}, qA = {H2[4], H2[5]}, qB = {H2[6], H2[7]},
         qC = {H3[0], H3[1]}, qD = {H3[2], H3[3]}, qE = {H3[4], H3[5]}, qF = {H3[6], H3[7]};
      // pin the window: all 4 b128 reads in flight together
      asm volatile("" : "+v"(q0), "+v"(q1), "+v"(q2), "+v"(q3),
                        "+v"(q4), "+v"(q5), "+v"(q6), "+v"(q7),
                        "+v"(q8), "+v"(q9), "+v"(qA), "+v"(qB),
                        "+v"(qC), "+v"(qD), "+v"(qE), "+v"(qF));

      FDOT16(Ra, Rb, Wr, __builtin_fmaf(x, xwr, cbr));
      FDOT16(Za, Zb, Wz, __builtin_fmaf(x, xwz, cbz));
      FDOT16(Na, Nb, Wn, cbh);

      const float ar = Ra + Rb;                  // already includes x-term+bias
      const float az = Za + Zb;
      const float r = __builtin_amdgcn_rcpf(1.0f + __builtin_amdgcn_exp2f(ar));
      const float z = __builtin_amdgcn_rcpf(1.0f + __builtin_amdgcn_exp2f(az));
      const float y = __builtin_fmaf(r, Na + Nb, __builtin_fmaf(x, xwn, cbn));
      const float n = __builtin_fmaf(-2.0f,
          __builtin_amdgcn_rcpf(1.0f + __builtin_amdgcn_exp2f(y)), 1.0f);
      h = __builtin_fmaf(z, h - n, n);           // (1-z)*n + z*h

      hbuf[rs][g] = (f16)h;                      // v_cvt + ds_write_b16
      __builtin_amdgcn_wave_barrier();           // wave-synchronous ordering
    }
    x4 = x4n;
  }

  // --- backward direction: exactly ONE GRU step from h0=0 on x[T-1] ---
  const float xl  = xbuf[rs][TT - 1];
  const float rb  = fast_sigm(__builtin_fmaf(xl, Wih_b[g],      bih_b[g]      + bhh_b[g]));
  const float zb  = fast_sigm(__builtin_fmaf(xl, Wih_b[HH + g], bih_b[HH + g] + bhh_b[HH + g]));
  const float xnb = __builtin_fmaf(xl, Wih_b[2*HH + g], bih_b[2*HH + g]);
  const float nb  = fast_tanh(__builtin_fmaf(rb, bhh_b[2*HH + g], xnb));
  const float hb  = nb - zb * nb;                // (1-zb)*nb + zb*0

  obuf[rs][g]      = h;                          // h_f (full fp32 state)
  obuf[rs][32 + g] = hb;                         // h_b
  __builtin_amdgcn_wave_barrier();

  // --- MLP head: sigmoid(W2 @ relu(W1 @ [h_f,h_b] + b1) + b2) ---
  const int j = g & 15;                          // lanes 16..31 duplicate
  const vf4* W1r = (const vf4*)(W1 + j * 64);
  const vf4* hc  = (const vf4*)&obuf[rs][0];
  vf4 a4 = W1r[0] * hc[0];
  #pragma unroll
  for (int q = 1; q < 16; ++q)
    a4 = __builtin_elementwise_fma(W1r[q], hc[q], a4);
  float acc = b1[j] + (a4.x + a4.y) + (a4.z + a4.w);
  float h1 = fmaxf(acc, 0.0f) * W2[j];
  h1 += __shfl_down(h1, 8, 16);
  h1 += __shfl_down(h1, 4, 16);
  h1 += __shfl_down(h1, 2, 16);
  h1 += __shfl_down(h1, 1, 16);
  if (g == 0) out[b] = fast_sigm(h1 + b2[0]);
}

extern "C" void kernel_launch(void* const* d_in, const int* in_sizes, int n_in,
                              void* d_out, int out_size, void* d_ws, size_t ws_size,
                              hipStream_t stream) {
  const float* X     = (const float*)d_in[0];
  const float* Wih_f = (const float*)d_in[1];
  const float* Whh_f = (const float*)d_in[2];
  const float* bih_f = (const float*)d_in[3];
  const float* bhh_f = (const float*)d_in[4];
  const float* Wih_b = (const float*)d_in[5];
  // d_in[6] = W_hh_b: unused — backward direction runs exactly one step from h0=0.
  const float* bih_b = (const float*)d_in[7];
  const float* bhh_b = (const float*)d_in[8];
  const float* W1    = (const float*)d_in[9];
  const float* b1    = (const float*)d_in[10];
  const float* W2    = (const float*)d_in[11];
  const float* b2    = (const float*)d_in[12];
  float* out = (float*)d_out;

  // 2048 rows / 8 rows per 256-thread block = 256 blocks = 1 block/CU,
  // 1024 waves = 1 wave/SIMD (2 rows per wave as half-waves).
  gru_bidir_head<<<256, 256, 0, stream>>>(X, Wih_f, Whh_f, bih_f, bhh_f,
                                          Wih_b, bih_b, bhh_b, W1, b1, W2, b2, out);
}